// Round 2
// baseline (481.837 us; speedup 1.0000x reference)
//
#include <hip/hip_runtime.h>

// CombineEmbeddings: out[b,s,:] = (idx[b,s] >= 0) ? patch[b, idx[b,s], :]
//                                                 : word[b, s, :]
// B=4, S=4096, P=2048, H=4096, fp32. Pure row-select copy — HBM-bound.
//
// R2: one block per (b,s) row. idx[blockIdx.x] is provably uniform -> s_load,
// amortized over the whole 16 KiB row. Each thread does 4 INDEPENDENT float4
// loads (cols tid, tid+256, tid+512, tid+768) -> 4x memory-level parallelism
// vs R1's single dependent idx->gather chain per 16 B.

#define BB 4
#define SS 4096
#define PP 2048
#define HH 4096
#define HV (HH / 4)   // 1024 float4 per row

__global__ __launch_bounds__(256) void CombineEmbeddings_50319836840460_kernel(
    const float4* __restrict__ word,    // [B*S, HV]
    const float4* __restrict__ patch,   // [B*P, HV]
    const int*    __restrict__ idx,     // [B*S]
    float4*       __restrict__ out)     // [B*S, HV]
{
    const int row = blockIdx.x;            // b*S + s
    const int b   = row >> 12;             // S = 4096 = 2^12
    const int id  = idx[row];              // uniform -> scalar load

    // Uniform source-row base pointer (s_cselect on SGPRs, no divergence).
    const float4* src = (id >= 0)
        ? patch + ((long long)(b * PP + id) << 10)
        : word  + ((long long)row << 10);

    const int c0 = threadIdx.x;
    float4 v0 = src[c0];
    float4 v1 = src[c0 + 256];
    float4 v2 = src[c0 + 512];
    float4 v3 = src[c0 + 768];

    float4* dst = out + ((long long)row << 10);
    dst[c0]       = v0;
    dst[c0 + 256] = v1;
    dst[c0 + 512] = v2;
    dst[c0 + 768] = v3;
}

extern "C" void kernel_launch(void* const* d_in, const int* in_sizes, int n_in,
                              void* d_out, int out_size, void* d_ws, size_t ws_size,
                              hipStream_t stream) {
    const float4* word  = (const float4*)d_in[0];
    const float4* patch = (const float4*)d_in[1];
    const int*    idx   = (const int*)d_in[2];
    float4*       out   = (float4*)d_out;

    const int grid = BB * SS;   // one block per output row: 16384
    CombineEmbeddings_50319836840460_kernel<<<grid, 256, 0, stream>>>(
        word, patch, idx, out);
}